// Round 11
// baseline (76.636 us; speedup 1.0000x reference)
//
#include <hip/hip_runtime.h>
#include <hip/hip_bf16.h>

constexpr int B = 8, N = 2048, FIN = 128, FOUT = 64;

typedef __attribute__((ext_vector_type(8))) short short8;
typedef __attribute__((ext_vector_type(4))) float f32x4;

// f32 pair -> packed bf16 (RNE) via v_cvt_pk_bf16_f32
__device__ __forceinline__ unsigned int pk_bf16(float lo, float hi) {
    union { __hip_bfloat162 h2; unsigned int u; } c;
    c.h2 = __float22bfloat162_rn(float2{lo, hi});
    return c.u;
}

// ---- kA: [blocks 0..255] h=inp@W -> hP (bf16, MFMA-B-frag packed), s1, s2
//      [blocks 256..511] adj -> 1-bit mask
// hP layout: [b][kb(64)][nf(4)][lane(64)] x 16B ; lane(g=lane>>4, r=lane&15)
//   holds h[i = kb*32 + g*8 + e][o = nf*16 + r], e = 0..7.
__global__ __launch_bounds__(512, 4) void kA(
        const float* __restrict__ inp, const float* __restrict__ W,
        const float* __restrict__ a, const int* __restrict__ adj,
        unsigned short* __restrict__ hP, float* __restrict__ s1,
        float* __restrict__ s2, unsigned long long* __restrict__ adjbits) {
    __shared__ unsigned short tile[64][72];
    int bx = blockIdx.x, t = threadIdx.x, w = t >> 6, lane = t & 63;

    if (bx >= 256) {                              // ---- adj bit-pack ----
        int row = (bx - 256) * 8 + w;             // [0,2048)
        const int* ar = adj + (size_t)row * N;
        unsigned long long* br = adjbits + (size_t)row * 32;
        #pragma unroll 8
        for (int wq = 0; wq < 32; ++wq) {
            unsigned long long m = __ballot(ar[wq * 64 + lane] > 0);
            if (lane == 0) br[wq] = m;
        }
        return;
    }
    // ---- h tile: batch b, rows i0..i0+63 ----
    int b = bx >> 5, i0 = (bx & 31) * 64;
    float a1 = a[lane], a2 = a[FOUT + lane];
    const float* ib = inp + ((size_t)b * N + i0 + w * 8) * FIN;
    float acc[8] = {};
    #pragma unroll 4
    for (int k = 0; k < FIN; ++k) {
        float wv = W[k * FOUT + lane];
        #pragma unroll
        for (int rr = 0; rr < 8; ++rr)
            acc[rr] = fmaf(ib[rr * FIN + k], wv, acc[rr]);
    }
    #pragma unroll
    for (int rr = 0; rr < 8; ++rr) {
        float p1 = acc[rr] * a1, p2 = acc[rr] * a2;
        #pragma unroll
        for (int off = 32; off > 0; off >>= 1) {
            p1 += __shfl_down(p1, off);
            p2 += __shfl_down(p2, off);
        }
        int row = i0 + w * 8 + rr;
        if (lane == 0) { s1[(size_t)b * N + row] = p1; s2[(size_t)b * N + row] = p2; }
        tile[w * 8 + rr][lane] = (unsigned short)(pk_bf16(acc[rr], 0.f) & 0xFFFF);
    }
    __syncthreads();
    // ---- packed write: 512 threads -> 512 x 16B entries -------------------
    {
        int kb_l = t >> 8;                        // 0..1 (32-row k-blocks)
        int nf   = (t >> 6) & 3;
        int ln   = t & 63;
        int g2 = ln >> 4, r2 = ln & 15;
        union { short8 s8; unsigned short u[8]; } tw;
        #pragma unroll
        for (int e = 0; e < 8; ++e)
            tw.u[e] = tile[kb_l * 32 + g2 * 8 + e][nf * 16 + r2];
        int kbg = (bx & 31) * 2 + kb_l;
        *(short8*)&hP[((((size_t)b * 64 + kbg) * 4 + nf) << 9) + ln * 8] = tw.s8;
    }
}

// ---- K2a v3: PV MFMA + row expsum -> rv, out ------------------------------
// 512 thr / 8 waves; 16 rows/block; wave kc owns cols [kc*256, kc*256+256).
// __launch_bounds__(512, 8): force VGPR <= 64 so 8 waves/SIMD are resident
// (R4 profile showed Occupancy 33% / VALUBusy 22% -> latency-bound at low
// occupancy; LDS 38.5KB allows 4 blocks/CU).
__global__ __launch_bounds__(512, 8) void k2a_pv(
        const float* __restrict__ s1g, const float* __restrict__ s2g,
        const unsigned long long* __restrict__ adjbits,
        const unsigned short* __restrict__ hP,
        float* __restrict__ rvg, float* __restrict__ out) {
    __shared__ float s2l[N];                 // 8 KB
    __shared__ float s1l[16];
    __shared__ float ps[8][16];
    __shared__ float rvl[16];
    __shared__ float red[7][16][68];         // 29.75 KB partial-C reduce

    int b = blockIdx.y, m0 = blockIdx.x * 16;
    int t = threadIdx.x, kc = t >> 6, lane = t & 63;
    int r = lane & 15, g = lane >> 4;

    { int j = t * 4; *(float4*)&s2l[j] = *(const float4*)&s2g[(size_t)b * N + j]; }
    if (t < 16) s1l[t] = s1g[(size_t)b * N + m0 + t];
    __syncthreads();

    float s1v = s1l[r];
    const unsigned long long* brow = adjbits + (size_t)(m0 + r) * 32 + kc * 4;
    const unsigned short* hpb = hP + (size_t)b * 64 * 4 * 512;

    f32x4 acc[4];
    #pragma unroll
    for (int nf = 0; nf < 4; ++nf)
        #pragma unroll
        for (int q = 0; q < 4; ++q) acc[nf][q] = 0.f;
    float rsum = 0.f;

    #pragma unroll
    for (int st = 0; st < 8; ++st) {
        int jb = kc * 256 + st * 32 + g * 8;
        unsigned int bits = (unsigned int)(brow[st >> 1] >> ((st & 1) * 32 + g * 8)) & 0xFFu;
        float4 sA = *(const float4*)&s2l[jb];
        float4 sB = *(const float4*)&s2l[jb + 4];
        float sj[8] = {sA.x, sA.y, sA.z, sA.w, sB.x, sB.y, sB.z, sB.w};
        float e8[8];
        #pragma unroll
        for (int e = 0; e < 8; ++e) {
            float x = s1v + sj[e];
            x = fmaxf(x, 0.2f * x);              // leaky_relu(0.2)
            float pe = __expf(x);                // |x| <~ 7 -> safe, no max-sub
            e8[e] = ((bits >> e) & 1u) ? pe : 0.f;
            rsum += e8[e];
        }
        union { short8 s8; unsigned int d[4]; } pk;
        #pragma unroll
        for (int e = 0; e < 4; ++e) pk.d[e] = pk_bf16(e8[2 * e], e8[2 * e + 1]);
        int kb = kc * 8 + st;
        const unsigned short* hs = hpb + (((size_t)kb * 4) << 9) + lane * 8;
        #pragma unroll
        for (int nf = 0; nf < 4; ++nf) {
            short8 Bf = *(const short8*)&hs[nf << 9];   // coalesced 1KB/wave
            acc[nf] = __builtin_amdgcn_mfma_f32_16x16x32_bf16(pk.s8, Bf, acc[nf], 0, 0, 0);
        }
    }
    rsum += __shfl_xor(rsum, 16);
    rsum += __shfl_xor(rsum, 32);
    if (lane < 16) ps[kc][r] = rsum;
    if (kc > 0) {
        #pragma unroll
        for (int nf = 0; nf < 4; ++nf)
            #pragma unroll
            for (int q = 0; q < 4; ++q)
                red[kc - 1][4 * g + q][nf * 16 + r] = acc[nf][q];
    }
    __syncthreads();
    if (t < 16) {
        float rv = 1.0f / (ps[0][t] + ps[1][t] + ps[2][t] + ps[3][t]
                         + ps[4][t] + ps[5][t] + ps[6][t] + ps[7][t]);
        rvl[t] = rv;
        rvg[(size_t)b * N + m0 + t] = rv;
    }
    __syncthreads();
    if (kc == 0) {
        #pragma unroll
        for (int nf = 0; nf < 4; ++nf) {
            #pragma unroll
            for (int q = 0; q < 4; ++q) {
                int m = 4 * g + q;               // C/D: row=(lane>>4)*4+reg
                int o = nf * 16 + r;             // C/D: col=lane&15
                float vv = acc[nf][q];
                #pragma unroll
                for (int z = 0; z < 7; ++z) vv += red[z][m][o];
                vv *= rvl[m];
                out[((size_t)b * N + m0 + m) * FOUT + o] = vv > 0.f ? vv : 0.f;
            }
        }
    }
}

// ---- K2b: stream att = e~ * rv. Block (i, by): batches by*4..+3, wave each.
__global__ __launch_bounds__(256, 8) void k2b_att(
        const float* __restrict__ s1g, const float* __restrict__ s2g,
        const unsigned long long* __restrict__ adjbits,
        const float* __restrict__ rvg, float* __restrict__ att) {
    int i = blockIdx.x;
    int t = threadIdx.x, w = t >> 6, lane = t & 63;
    int b = blockIdx.y * 4 + w;
    const unsigned long long* brow = adjbits + (size_t)i * 32;
    float s1v = s1g[(size_t)b * N + i];
    float rv  = rvg[(size_t)b * N + i];
    const float* s2b = s2g + (size_t)b * N;
    float* orow = att + ((size_t)b * N + i) * N;
    #pragma unroll
    for (int it = 0; it < 8; ++it) {
        int j = it * 256 + lane * 4;
        unsigned int bits = (unsigned int)(brow[j >> 6] >> (j & 63)) & 0xFu;
        float4 sv = *(const float4*)&s2b[j];
        float x0 = s1v + sv.x; x0 = fmaxf(x0, 0.2f * x0);
        float x1 = s1v + sv.y; x1 = fmaxf(x1, 0.2f * x1);
        float x2 = s1v + sv.z; x2 = fmaxf(x2, 0.2f * x2);
        float x3 = s1v + sv.w; x3 = fmaxf(x3, 0.2f * x3);
        float4 o;
        o.x = (bits & 1u) ? __expf(x0) * rv : 0.f;
        o.y = (bits & 2u) ? __expf(x1) * rv : 0.f;
        o.z = (bits & 4u) ? __expf(x2) * rv : 0.f;
        o.w = (bits & 8u) ? __expf(x3) * rv : 0.f;
        *(float4*)&orow[j] = o;                   // 1KB/wave contiguous
    }
}

extern "C" void kernel_launch(void* const* d_in, const int* in_sizes, int n_in,
                              void* d_out, int out_size, void* d_ws, size_t ws_size,
                              hipStream_t stream) {
    const float* inp = (const float*)d_in[0];   // (8,2048,128) f32
    const int*   adj = (const int*)d_in[1];     // (2048,2048) i32
    const float* W   = (const float*)d_in[2];   // (128,64) f32
    const float* a   = (const float*)d_in[3];   // (128,1) f32

    float* out = (float*)d_out;                        // (8,2048,64)
    float* att = out + (size_t)B * N * FOUT;           // (8,2048,2048)

    unsigned short* hP = (unsigned short*)d_ws;        // 2 MB bf16, packed
    float* s1  = (float*)(hP + (size_t)B * FOUT * N);  // 64 KB
    float* s2  = s1 + (size_t)B * N;                   // 64 KB
    float* rvg = s2 + (size_t)B * N;                   // 64 KB
    unsigned long long* adjbits = (unsigned long long*)(rvg + (size_t)B * N); // 512 KB

    kA<<<512, 512, 0, stream>>>(inp, W, a, adj, hP, s1, s2, adjbits);
    dim3 g2a(N / 16, B);
    k2a_pv<<<g2a, 512, 0, stream>>>(s1, s2, adjbits, hP, rvg, out);
    dim3 g2b(N, 2);
    k2b_att<<<g2b, 256, 0, stream>>>(s1, s2, adjbits, rvg, att);
}

// Round 12
// 63.412 us; speedup vs baseline: 1.2085x; 1.2085x over previous
//
#include <hip/hip_runtime.h>
#include <hip/hip_bf16.h>

constexpr int B = 8, N = 2048, FIN = 128, FOUT = 64;

typedef __attribute__((ext_vector_type(8))) short short8;
typedef __attribute__((ext_vector_type(4))) float f32x4;

// f32 pair -> packed bf16 (RNE) via v_cvt_pk_bf16_f32
__device__ __forceinline__ unsigned int pk_bf16(float lo, float hi) {
    union { __hip_bfloat162 h2; unsigned int u; } c;
    c.h2 = __float22bfloat162_rn(float2{lo, hi});
    return c.u;
}
__device__ __forceinline__ unsigned short f2bf(float f) {
    return (unsigned short)(pk_bf16(f, 0.f) & 0xFFFFu);
}

// ---- kA v2: [blocks 0..127] h = inp@W via bf16 MFMA -> hP; s1/s2 in f32
//      [blocks 128..383] adj -> 1-bit mask
// s1 = inp @ (W@a1) computed in f32 DURING the inp load (before bf16
// rounding) -- keeps logits f32-exact. h itself tolerates bf16 inputs
// (it is already bf16-quantized for hP; errors average down in att@h).
// hP layout unchanged: [b][kb(64)][nf(4)][lane(64)] x 16B.
__global__ __launch_bounds__(512, 2) void kA(
        const float* __restrict__ inp, const float* __restrict__ W,
        const float* __restrict__ a, const int* __restrict__ adj,
        unsigned short* __restrict__ hP, float* __restrict__ s1,
        float* __restrict__ s2, unsigned long long* __restrict__ adjbits) {
    __shared__ float wa1l[128], wa2l[128];
    __shared__ unsigned short wT[64][136];    // W^T bf16, padded (272B rows)
    __shared__ unsigned short aT[128][136];   // inp tile bf16 / h tile reuse

    int bx = blockIdx.x, t = threadIdx.x, w = t >> 6, lane = t & 63;

    if (bx >= 128) {                              // ---- adj bit-pack ----
        int row = (bx - 128) * 8 + w;             // [0,2048)
        const int* ar = adj + (size_t)row * N;
        unsigned long long* br = adjbits + (size_t)row * 32;
        #pragma unroll 8
        for (int wq = 0; wq < 32; ++wq) {
            unsigned long long m = __ballot(ar[wq * 64 + lane] > 0);
            if (lane == 0) br[wq] = m;
        }
        return;
    }

    int b = bx >> 4, i0 = (bx & 15) * 128;

    // ---- phase 1: wa1/wa2 = W@a (f32)  ||  stage W^T -> bf16 LDS ----------
    if (t < 128) {
        const float* wr = W + t * FOUT;
        float acc1 = 0.f;
        #pragma unroll 16
        for (int o = 0; o < 64; ++o) acc1 = fmaf(wr[o], a[o], acc1);
        wa1l[t] = acc1;
    } else if (t < 256) {
        int k = t - 128;
        const float* wr = W + k * FOUT;
        float acc2 = 0.f;
        #pragma unroll 16
        for (int o = 0; o < 64; ++o) acc2 = fmaf(wr[o], a[64 + o], acc2);
        wa2l[k] = acc2;
    } else {
        int t2 = t - 256;
        int o = t2 & 63, kg = t2 >> 6;            // kg 0..3
        #pragma unroll 8
        for (int kk = 0; kk < 32; ++kk) {
            int k = kg * 32 + kk;
            wT[o][k] = f2bf(W[k * FOUT + o]);     // coalesced across o
        }
    }
    __syncthreads();

    // ---- phase 2: load inp f32, s1/s2 dots (f32), fill aT (bf16) ----------
    {
        int row = t >> 2, seg = t & 3;            // row 0..127, seg 0..3
        const float* ip = inp + ((size_t)b * N + i0 + row) * FIN + seg * 32;
        float s1p = 0.f, s2p = 0.f;
        #pragma unroll
        for (int q = 0; q < 8; ++q) {
            float4 v = *(const float4*)&ip[q * 4];
            int k = seg * 32 + q * 4;
            s1p += v.x * wa1l[k] + v.y * wa1l[k + 1] + v.z * wa1l[k + 2] + v.w * wa1l[k + 3];
            s2p += v.x * wa2l[k] + v.y * wa2l[k + 1] + v.z * wa2l[k + 2] + v.w * wa2l[k + 3];
            unsigned int* dst = (unsigned int*)&aT[row][k];
            dst[0] = pk_bf16(v.x, v.y);
            dst[1] = pk_bf16(v.z, v.w);
        }
        s1p += __shfl_xor(s1p, 1); s1p += __shfl_xor(s1p, 2);
        s2p += __shfl_xor(s2p, 1); s2p += __shfl_xor(s2p, 2);
        if (seg == 0) {
            s1[(size_t)b * N + i0 + row] = s1p;
            s2[(size_t)b * N + i0 + row] = s2p;
        }
    }
    __syncthreads();

    // ---- phase 3: MFMA  h[mloc..mloc+15][0..63] per wave -------------------
    int r = lane & 15, g = lane >> 4;
    int mloc = w * 16;
    f32x4 acc[4];
    #pragma unroll
    for (int nf = 0; nf < 4; ++nf)
        #pragma unroll
        for (int q = 0; q < 4; ++q) acc[nf][q] = 0.f;
    #pragma unroll
    for (int ks = 0; ks < 4; ++ks) {
        short8 Af = *(const short8*)&aT[mloc + r][ks * 32 + g * 8];
        #pragma unroll
        for (int nf = 0; nf < 4; ++nf) {
            short8 Bf = *(const short8*)&wT[nf * 16 + r][ks * 32 + g * 8];
            acc[nf] = __builtin_amdgcn_mfma_f32_16x16x32_bf16(Af, Bf, acc[nf], 0, 0, 0);
        }
    }
    __syncthreads();                               // all aT reads complete

    // ---- phase 4: h tile (bf16) into aT space ------------------------------
    #pragma unroll
    for (int nf = 0; nf < 4; ++nf)
        #pragma unroll
        for (int q = 0; q < 4; ++q)
            aT[mloc + g * 4 + q][nf * 16 + r] = f2bf(acc[nf][q]);  // C/D layout
    __syncthreads();

    // ---- phase 5: pack 1024 x 16B hP entries (layout identical to R11) ----
    #pragma unroll
    for (int half = 0; half < 2; ++half) {
        int idx = t + half * 512;                  // 0..1023
        int kb_l = idx >> 8, nf = (idx >> 6) & 3, ln = idx & 63;
        int g2 = ln >> 4, r2 = ln & 15;
        union { short8 s8; unsigned short u[8]; } tw;
        #pragma unroll
        for (int e = 0; e < 8; ++e)
            tw.u[e] = aT[kb_l * 32 + g2 * 8 + e][nf * 16 + r2];
        int kbg = (bx & 15) * 4 + kb_l;
        *(short8*)&hP[((((size_t)b * 64 + kbg) * 4 + nf) << 9) + ln * 8] = tw.s8;
    }
}

// ---- K2a: PV MFMA + row expsum -> rv, out (unchanged from R11) ------------
__global__ __launch_bounds__(512, 8) void k2a_pv(
        const float* __restrict__ s1g, const float* __restrict__ s2g,
        const unsigned long long* __restrict__ adjbits,
        const unsigned short* __restrict__ hP,
        float* __restrict__ rvg, float* __restrict__ out) {
    __shared__ float s2l[N];
    __shared__ float s1l[16];
    __shared__ float ps[8][16];
    __shared__ float rvl[16];
    __shared__ float red[7][16][68];

    int b = blockIdx.y, m0 = blockIdx.x * 16;
    int t = threadIdx.x, kc = t >> 6, lane = t & 63;
    int r = lane & 15, g = lane >> 4;

    { int j = t * 4; *(float4*)&s2l[j] = *(const float4*)&s2g[(size_t)b * N + j]; }
    if (t < 16) s1l[t] = s1g[(size_t)b * N + m0 + t];
    __syncthreads();

    float s1v = s1l[r];
    const unsigned long long* brow = adjbits + (size_t)(m0 + r) * 32 + kc * 4;
    const unsigned short* hpb = hP + (size_t)b * 64 * 4 * 512;

    f32x4 acc[4];
    #pragma unroll
    for (int nf = 0; nf < 4; ++nf)
        #pragma unroll
        for (int q = 0; q < 4; ++q) acc[nf][q] = 0.f;
    float rsum = 0.f;

    #pragma unroll
    for (int st = 0; st < 8; ++st) {
        int jb = kc * 256 + st * 32 + g * 8;
        unsigned int bits = (unsigned int)(brow[st >> 1] >> ((st & 1) * 32 + g * 8)) & 0xFFu;
        float4 sA = *(const float4*)&s2l[jb];
        float4 sB = *(const float4*)&s2l[jb + 4];
        float sj[8] = {sA.x, sA.y, sA.z, sA.w, sB.x, sB.y, sB.z, sB.w};
        float e8[8];
        #pragma unroll
        for (int e = 0; e < 8; ++e) {
            float x = s1v + sj[e];
            x = fmaxf(x, 0.2f * x);
            float pe = __expf(x);
            e8[e] = ((bits >> e) & 1u) ? pe : 0.f;
            rsum += e8[e];
        }
        union { short8 s8; unsigned int d[4]; } pk;
        #pragma unroll
        for (int e = 0; e < 4; ++e) pk.d[e] = pk_bf16(e8[2 * e], e8[2 * e + 1]);
        int kb = kc * 8 + st;
        const unsigned short* hs = hpb + (((size_t)kb * 4) << 9) + lane * 8;
        #pragma unroll
        for (int nf = 0; nf < 4; ++nf) {
            short8 Bf = *(const short8*)&hs[nf << 9];
            acc[nf] = __builtin_amdgcn_mfma_f32_16x16x32_bf16(pk.s8, Bf, acc[nf], 0, 0, 0);
        }
    }
    rsum += __shfl_xor(rsum, 16);
    rsum += __shfl_xor(rsum, 32);
    if (lane < 16) ps[kc][r] = rsum;
    if (kc > 0) {
        #pragma unroll
        for (int nf = 0; nf < 4; ++nf)
            #pragma unroll
            for (int q = 0; q < 4; ++q)
                red[kc - 1][4 * g + q][nf * 16 + r] = acc[nf][q];
    }
    __syncthreads();
    if (t < 16) {
        float rv = 1.0f / (ps[0][t] + ps[1][t] + ps[2][t] + ps[3][t]
                         + ps[4][t] + ps[5][t] + ps[6][t] + ps[7][t]);
        rvl[t] = rv;
        rvg[(size_t)b * N + m0 + t] = rv;
    }
    __syncthreads();
    if (kc == 0) {
        #pragma unroll
        for (int nf = 0; nf < 4; ++nf) {
            #pragma unroll
            for (int q = 0; q < 4; ++q) {
                int m = 4 * g + q;
                int o = nf * 16 + r;
                float vv = acc[nf][q];
                #pragma unroll
                for (int z = 0; z < 7; ++z) vv += red[z][m][o];
                vv *= rvl[m];
                out[((size_t)b * N + m0 + m) * FOUT + o] = vv > 0.f ? vv : 0.f;
            }
        }
    }
}

// ---- K2b: stream att = e~ * rv (unchanged from R11) -----------------------
__global__ __launch_bounds__(256, 8) void k2b_att(
        const float* __restrict__ s1g, const float* __restrict__ s2g,
        const unsigned long long* __restrict__ adjbits,
        const float* __restrict__ rvg, float* __restrict__ att) {
    int i = blockIdx.x;
    int t = threadIdx.x, w = t >> 6, lane = t & 63;
    int b = blockIdx.y * 4 + w;
    const unsigned long long* brow = adjbits + (size_t)i * 32;
    float s1v = s1g[(size_t)b * N + i];
    float rv  = rvg[(size_t)b * N + i];
    const float* s2b = s2g + (size_t)b * N;
    float* orow = att + ((size_t)b * N + i) * N;
    #pragma unroll
    for (int it = 0; it < 8; ++it) {
        int j = it * 256 + lane * 4;
        unsigned int bits = (unsigned int)(brow[j >> 6] >> (j & 63)) & 0xFu;
        float4 sv = *(const float4*)&s2b[j];
        float x0 = s1v + sv.x; x0 = fmaxf(x0, 0.2f * x0);
        float x1 = s1v + sv.y; x1 = fmaxf(x1, 0.2f * x1);
        float x2 = s1v + sv.z; x2 = fmaxf(x2, 0.2f * x2);
        float x3 = s1v + sv.w; x3 = fmaxf(x3, 0.2f * x3);
        float4 o;
        o.x = (bits & 1u) ? __expf(x0) * rv : 0.f;
        o.y = (bits & 2u) ? __expf(x1) * rv : 0.f;
        o.z = (bits & 4u) ? __expf(x2) * rv : 0.f;
        o.w = (bits & 8u) ? __expf(x3) * rv : 0.f;
        *(float4*)&orow[j] = o;
    }
}

extern "C" void kernel_launch(void* const* d_in, const int* in_sizes, int n_in,
                              void* d_out, int out_size, void* d_ws, size_t ws_size,
                              hipStream_t stream) {
    const float* inp = (const float*)d_in[0];   // (8,2048,128) f32
    const int*   adj = (const int*)d_in[1];     // (2048,2048) i32
    const float* W   = (const float*)d_in[2];   // (128,64) f32
    const float* a   = (const float*)d_in[3];   // (128,1) f32

    float* out = (float*)d_out;                        // (8,2048,64)
    float* att = out + (size_t)B * N * FOUT;           // (8,2048,2048)

    unsigned short* hP = (unsigned short*)d_ws;        // 2 MB bf16, packed
    float* s1  = (float*)(hP + (size_t)B * FOUT * N);  // 64 KB
    float* s2  = s1 + (size_t)B * N;                   // 64 KB
    float* rvg = s2 + (size_t)B * N;                   // 64 KB
    unsigned long long* adjbits = (unsigned long long*)(rvg + (size_t)B * N); // 512 KB

    kA<<<384, 512, 0, stream>>>(inp, W, a, adj, hP, s1, s2, adjbits);
    dim3 g2a(N / 16, B);
    k2a_pv<<<g2a, 512, 0, stream>>>(s1, s2, adjbits, hP, rvg, out);
    dim3 g2b(N, 2);
    k2b_att<<<g2b, 256, 0, stream>>>(s1, s2, adjbits, rvg, att);
}